// Round 9
// baseline (392.811 us; speedup 1.0000x reference)
//
#include <hip/hip_runtime.h>

typedef _Float16 f16;
typedef f16 half8 __attribute__((ext_vector_type(8)));
typedef f16 f16x4 __attribute__((ext_vector_type(4)));
typedef float f32x4 __attribute__((ext_vector_type(4)));

#define GLOAD_LDS16(gsrc, ldst)                                                              \
  __builtin_amdgcn_global_load_lds((const __attribute__((address_space(1))) void*)(gsrc),    \
                                   (__attribute__((address_space(3))) void*)(ldst), 16, 0, 0)

constexpr float SCALE = 0.125f;  // 64^-0.5
// Q pre-scale folds log2(e): softmax runs in exp2 domain (raw v_exp_f32).
constexpr float SCALE_L2E = 0.125f * 1.4426950408889634f;

// pack two f32 -> two f16 in one u32 (v_cvt_pkrtz_f16_f32).
static __device__ __forceinline__ unsigned pk2(float a, float b) {
  return __builtin_bit_cast(unsigned, __builtin_amdgcn_cvt_pkrtz(a, b));
}

// ---------------- convert f32 -> f16, vectorized x4 ----------------
__global__ __launch_bounds__(256) void k_cvt(const float4* __restrict__ in,
                                             f16x4* __restrict__ out, int n4) {
  int i = blockIdx.x * 256 + threadIdx.x;
  if (i < n4) {
    float4 v = in[i];
    f16x4 o;
    o[0] = (f16)v.x; o[1] = (f16)v.y; o[2] = (f16)v.z; o[3] = (f16)v.w;
    out[i] = o;
  }
}

// ---------------- transpose f32 [R][C] -> f16 [C][R] (generic, for W_out) ----
__global__ __launch_bounds__(256) void k_transpose(const float* __restrict__ in,
                                                   f16* __restrict__ out, int R, int C) {
  __shared__ float t[32][33];
  int c0 = blockIdx.x * 32, r0 = blockIdx.y * 32;
  int tx = threadIdx.x, ty = threadIdx.y;
  for (int i = ty; i < 32; i += 8) t[i][tx] = in[(size_t)(r0 + i) * C + c0 + tx];
  __syncthreads();
  for (int i = ty; i < 32; i += 8) out[(size_t)(c0 + i) * R + r0 + tx] = (f16)t[tx][i];
}

// -------- W_qkv transpose with column-permuted output row order ----------
// out row e' = k*1024 + h*64 + d  (kills epilogue write amplification).
__global__ __launch_bounds__(256) void k_transpose_qkv(const float* __restrict__ in,
                                                       f16* __restrict__ out) {
  __shared__ float t[32][33];
  int c0 = blockIdx.x * 32, r0 = blockIdx.y * 32;
  int tx = threadIdx.x, ty = threadIdx.y;
  for (int i = ty; i < 32; i += 8) t[i][tx] = in[(size_t)(r0 + i) * 3072 + c0 + tx];
  __syncthreads();
  for (int i = ty; i < 32; i += 8) {
    const int e = c0 + i;
    const int d = e / 48, rem = e - d * 48;
    const int k = rem >> 4, h = rem & 15;
    const int ep = k * 1024 + h * 64 + d;
    out[(size_t)ep * 1024 + r0 + tx] = (f16)t[tx][i];
  }
}

// ---------------- GEMM (unchanged) ----------------
template <int MODE>
__global__ __launch_bounds__(256) void k_gemm(const f16* __restrict__ A,
                                              const f16* __restrict__ Bt,
                                              float* __restrict__ C,
                                              f16* __restrict__ Qp,
                                              f16* __restrict__ Kp,
                                              f16* __restrict__ Vt) {
  constexpr int K = 1024, BK = 64;
  __shared__ alignas(16) f16 smem[128 * 128];
  f16* As = smem;
  f16* Bs = smem + 128 * 64;
  const int tid = threadIdx.x;
  const int w = tid >> 6, lane = tid & 63;
  const int g = lane >> 4, lr = lane & 15;
  const int wr = w >> 1, wc = w & 1;
  const int m0 = blockIdx.y * 128, n0 = blockIdx.x * 128;
  const int srow = lane >> 3;
  const int scol = ((lane & 7) ^ srow) << 3;

  f32x4 acc[4][4] = {};

  for (int kt = 0; kt < K; kt += BK) {
    __syncthreads();
#pragma unroll
    for (int i = 0; i < 4; ++i) {
      const int chunk = w * 4 + i;
      const int row = chunk * 8 + srow;
      GLOAD_LDS16(A + (size_t)(m0 + row) * K + kt + scol, &As[chunk * 512]);
      GLOAD_LDS16(Bt + (size_t)(n0 + row) * K + kt + scol, &Bs[chunk * 512]);
    }
    __syncthreads();
#pragma unroll
    for (int c = 0; c < 2; ++c) {
      half8 af[4], bf[4];
#pragma unroll
      for (int m = 0; m < 4; ++m) {
        const int ra = wr * 64 + m * 16 + lr;
        const int off = ra * 128 + ((((c << 2) | g) ^ (ra & 7)) << 4);
        af[m] = *(const half8*)((const char*)As + off);
      }
#pragma unroll
      for (int n = 0; n < 4; ++n) {
        const int rb = wc * 64 + n * 16 + lr;
        const int off = rb * 128 + ((((c << 2) | g) ^ (rb & 7)) << 4);
        bf[n] = *(const half8*)((const char*)Bs + off);
      }
#pragma unroll
      for (int m = 0; m < 4; ++m)
#pragma unroll
        for (int n = 0; n < 4; ++n)
          acc[m][n] = __builtin_amdgcn_mfma_f32_16x16x32_f16(af[m], bf[n], acc[m][n], 0, 0, 0);
    }
  }

  if constexpr (MODE == 0) {
    const int sec = n0 >> 10;
    const int base = n0 & 1023;
    const int b = m0 >> 11;
    if (sec < 2) {
      f16* __restrict__ dst = (sec == 0) ? Qp : Kp;
      const float mul = (sec == 0) ? SCALE_L2E : 1.0f;
#pragma unroll
      for (int n = 0; n < 4; ++n) {
        const int idx = base + wc * 64 + n * 16 + lr;
        const int h = idx >> 6, d = idx & 63;
        f16* __restrict__ dh = dst + ((size_t)(b * 16 + h) * 2048) * 64 + d;
#pragma unroll
        for (int m = 0; m < 4; ++m)
#pragma unroll
          for (int r = 0; r < 4; ++r) {
            const int nn = (m0 & 2047) + wr * 64 + m * 16 + 4 * g + r;
            dh[(size_t)nn * 64] = (f16)(acc[m][n][r] * mul);
          }
      }
    } else {
      char* sb = (char*)smem;
      __syncthreads();
#pragma unroll
      for (int m = 0; m < 4; ++m)
#pragma unroll
        for (int n = 0; n < 4; ++n) {
          const int col = wc * 64 + n * 16 + lr;
          const int tok0 = wr * 64 + m * 16 + 4 * g;
          f16x4 v4;
#pragma unroll
          for (int r = 0; r < 4; ++r) v4[r] = (f16)acc[m][n][r];
          *(f16x4*)(sb + col * 256 + ((tok0 * 2) ^ ((col & 15) << 4))) = v4;
        }
      __syncthreads();
      const int nn0 = m0 & 2047;
#pragma unroll
      for (int pass = 0; pass < 8; ++pass) {
        const int c = w * 32 + pass * 4 + g;
        const int idx = base + c;
        const int h = idx >> 6, d = idx & 63;
        const half8 v = *(const half8*)(sb + c * 256 + ((lr * 16) ^ ((c & 15) << 4)));
        *(half8*)(Vt + ((size_t)(b * 16 + h) * 64 + d) * 2048 + nn0 + lr * 8) = v;
      }
    }
  } else {
#pragma unroll
    for (int m = 0; m < 4; ++m)
#pragma unroll
      for (int n = 0; n < 4; ++n)
#pragma unroll
        for (int r = 0; r < 4; ++r)
          C[(size_t)(m0 + wr * 64 + m * 16 + 4 * g + r) * 1024 +
            (n0 + wc * 64 + n * 16 + lr)] = acc[m][n][r];
  }
}

// ---------------- causal flash attention v6: K-split (flash-decoding) --------
// Work unit = (bh, 32-row q-tile qt, K-chunk of <=8 64-key tiles): 5120 single-
// wave blocks -> ~5 waves/SIMD (v5 was locked at 2). v5's swapped-operand
// in-lane softmax core unchanged. qt<16 (single chunk) writes O directly;
// multi-chunk units write unnormalized f16 partials + (m,l), merged by k_merge.
__global__ __launch_bounds__(64, 5) void k_attn(const f16* __restrict__ Q,
                                                const f16* __restrict__ Kp,
                                                const f16* __restrict__ Vt,
                                                f16* __restrict__ O,
                                                f16* __restrict__ Opart,
                                                float2* __restrict__ ml) {
  __shared__ alignas(16) char pl[4608];  // [32 rows][144 B]
  const int lane = threadIdx.x;
  const int g = lane >> 4, lr = lane & 15;
  // XCD-chunked bijective swizzle (5120 % 8 == 0)
  const int raw = blockIdx.x;
  const int uid = (raw & 7) * 640 + (raw >> 3);
  const int bh = uid / 160;
  const int w = uid - bh * 160;
  int qt, ks;
  if (w < 16)       { qt = w;                     ks = 0; }
  else if (w < 48)  { qt = 16 + ((w - 16) >> 1);  ks = (w - 16) & 1; }
  else if (w < 96)  { const int v = (w - 48) / 3; qt = 32 + v; ks = (w - 48) - 3 * v; }
  else              { qt = 48 + ((w - 96) >> 2);  ks = (w - 96) & 3; }
  const bool single = (w < 16);
  const int j = qt >> 1;               // last K-tile index for this q-tile
  const int kt0 = ks << 3;
  const int kt1 = min(kt0 + 7, j);
  const int q0 = qt * 32;
  const int punit = bh * 144 + (w - 16);  // valid iff !single

  const f16* __restrict__ Qb = Q + (size_t)bh * (2048 * 64);
  const f16* __restrict__ Kb = Kp + (size_t)bh * (2048 * 64);
  const f16* __restrict__ Vb = Vt + (size_t)bh * (64 * 2048);

  // Q as B-operand: col = lr -> q-row q0+16f+lr, k = 8g+i -> d
  half8 qf[2][2];
#pragma unroll
  for (int f = 0; f < 2; ++f)
#pragma unroll
    for (int c = 0; c < 2; ++c)
      qf[f][c] = *(const half8*)(Qb + (size_t)(q0 + 16 * f + lr) * 64 + 32 * c + 8 * g);

  f32x4 acc[2][4] = {};  // O^T: acc[f][nb][r] = O^T[d=16nb+4g+r][q=q0+16f+lr]
  float mrow[2] = {-INFINITY, -INFINITY};
  float lrow[2] = {0.f, 0.f};

  for (int kt = kt0; kt <= kt1; ++kt) {
    const int k0 = kt * 64;
    // K as A-operand: row = lr -> key k0+16jj+lr, k = 8g+i -> d
    half8 kf[4][2];
#pragma unroll
    for (int jj = 0; jj < 4; ++jj)
#pragma unroll
      for (int c = 0; c < 2; ++c)
        kf[jj][c] = *(const half8*)(Kb + (size_t)(k0 + 16 * jj + lr) * 64 + 32 * c + 8 * g);

    // ---- S^T = K Q^T : lane holds S^T[key=k0+16jj+4g+r][q=q0+16f+lr] ----
    __builtin_amdgcn_s_setprio(1);
    f32x4 st[2][4];
#pragma unroll
    for (int f = 0; f < 2; ++f)
#pragma unroll
      for (int jj = 0; jj < 4; ++jj) {
        f32x4 z = {};
        z = __builtin_amdgcn_mfma_f32_16x16x32_f16(kf[jj][0], qf[f][0], z, 0, 0, 0);
        st[f][jj] = __builtin_amdgcn_mfma_f32_16x16x32_f16(kf[jj][1], qf[f][1], z, 0, 0, 0);
      }
    __builtin_amdgcn_s_setprio(0);

    // V as A-operand (issued early; latency hides under softmax)
    half8 va[4][2];
#pragma unroll
    for (int nb = 0; nb < 4; ++nb)
#pragma unroll
      for (int c = 0; c < 2; ++c)
        va[nb][c] = *(const half8*)(Vb + (size_t)(16 * nb + lr) * 2048 + k0 + 32 * c + 8 * g);

    // causal mask (only the diagonal tile triggers; only last chunk has it)
    if (k0 + 63 > q0) {
#pragma unroll
      for (int f = 0; f < 2; ++f)
#pragma unroll
        for (int jj = 0; jj < 4; ++jj) {
          const int keyb = k0 + 16 * jj + 4 * g;
          const int q = q0 + 16 * f + lr;
#pragma unroll
          for (int r = 0; r < 4; ++r)
            if (keyb + r > q) st[f][jj][r] = -INFINITY;
        }
    }

    // ---- in-lane online softmax (exp2 domain) + packed P write ----
    float sfv[2];
#pragma unroll
    for (int f = 0; f < 2; ++f) {
      f32x4 m4 = st[f][0];
#pragma unroll
      for (int jj = 1; jj < 4; ++jj)
#pragma unroll
        for (int r = 0; r < 4; ++r) m4[r] = fmaxf(m4[r], st[f][jj][r]);
      float tm = fmaxf(fmaxf(m4[0], m4[1]), fmaxf(m4[2], m4[3]));
      tm = fmaxf(tm, __shfl_xor(tm, 16));
      tm = fmaxf(tm, __shfl_xor(tm, 32));
      const float mn = fmaxf(mrow[f], tm);
      sfv[f] = __builtin_amdgcn_exp2f(mrow[f] - mn);
      mrow[f] = mn;
      f32x4 s4 = {};
#pragma unroll
      for (int jj = 0; jj < 4; ++jj) {
#pragma unroll
        for (int r = 0; r < 4; ++r) {
          st[f][jj][r] = __builtin_amdgcn_exp2f(st[f][jj][r] - mn);
          s4[r] += st[f][jj][r];
        }
        const int rb = (16 * f + lr) * 144 + 32 * jj + 8 * g;
        *(unsigned*)(pl + rb) = pk2(st[f][jj][0], st[f][jj][1]);
        *(unsigned*)(pl + rb + 4) = pk2(st[f][jj][2], st[f][jj][3]);
      }
      float rs = (s4[0] + s4[1]) + (s4[2] + s4[3]);
      rs += __shfl_xor(rs, 16);
      rs += __shfl_xor(rs, 32);
      lrow[f] = lrow[f] * sfv[f] + rs;
#pragma unroll
      for (int nb = 0; nb < 4; ++nb)
#pragma unroll
        for (int r = 0; r < 4; ++r) acc[f][nb][r] *= sfv[f];
    }

    asm volatile("s_waitcnt lgkmcnt(0)" ::: "memory");
    __builtin_amdgcn_sched_barrier(0);
    // P^T as B-operand: col = lr -> q, k = 8g+i -> key 32c+8g+i
    half8 pf[2][2];
#pragma unroll
    for (int f = 0; f < 2; ++f)
#pragma unroll
      for (int c = 0; c < 2; ++c)
        pf[f][c] = *(const half8*)(pl + (16 * f + lr) * 144 + 64 * c + 16 * g);

    __builtin_amdgcn_s_setprio(1);
#pragma unroll
    for (int f = 0; f < 2; ++f)
#pragma unroll
      for (int nb = 0; nb < 4; ++nb) {
        acc[f][nb] = __builtin_amdgcn_mfma_f32_16x16x32_f16(va[nb][0], pf[f][0], acc[f][nb], 0, 0, 0);
        acc[f][nb] = __builtin_amdgcn_mfma_f32_16x16x32_f16(va[nb][1], pf[f][1], acc[f][nb], 0, 0, 0);
      }
    __builtin_amdgcn_s_setprio(0);
    __builtin_amdgcn_sched_barrier(0);  // P reads precede next tile's writes
  }

  // ---- epilogue: pack (normalized or raw) O^T -> LDS -> coalesced stores ----
#pragma unroll
  for (int f = 0; f < 2; ++f) {
    const float inv = single ? (1.f / lrow[f]) : 1.f;
#pragma unroll
    for (int nb = 0; nb < 4; ++nb) {
      const int rb = (16 * f + lr) * 144 + 32 * nb + 8 * g;
      *(unsigned*)(pl + rb) = pk2(acc[f][nb][0] * inv, acc[f][nb][1] * inv);
      *(unsigned*)(pl + rb + 4) = pk2(acc[f][nb][2] * inv, acc[f][nb][3] * inv);
    }
  }
  asm volatile("s_waitcnt lgkmcnt(0)" ::: "memory");
  __builtin_amdgcn_sched_barrier(0);
  const int row = lane >> 1, half = lane & 1;  // 2 lanes per q-row
  if (single) {
    const int b = bh >> 4, h = bh & 15;
    f16* orow = O + ((size_t)(b * 2048 + q0 + row) * 1024) + h * 64 + 32 * half;
#pragma unroll
    for (int k = 0; k < 4; ++k)
      *(half8*)(orow + 8 * k) = *(const half8*)(pl + row * 144 + 64 * half + 16 * k);
  } else {
    if (g == 0) {
#pragma unroll
      for (int f = 0; f < 2; ++f)
        ml[punit * 32 + 16 * f + lr] = make_float2(mrow[f], lrow[f]);
    }
    f16* orow = Opart + (size_t)punit * 2048 + row * 64 + 32 * half;
#pragma unroll
    for (int k = 0; k < 4; ++k)
      *(half8*)(orow + 8 * k) = *(const half8*)(pl + row * 144 + 64 * half + 16 * k);
  }
}

// ---------------- merge partial attention results (qt >= 16) ----------------
__global__ __launch_bounds__(64) void k_merge(const f16* __restrict__ Opart,
                                              const float2* __restrict__ ml,
                                              f16* __restrict__ O) {
  const int blk = blockIdx.x;  // bh*48 + (qt-16)
  const int bh = blk / 48;
  const int qt = 16 + (blk - bh * 48);
  const int nu = (qt < 32) ? 2 : (qt < 48) ? 3 : 4;
  const int off = (qt < 32) ? (qt - 16) * 2 : (qt < 48) ? 32 + (qt - 32) * 3 : 80 + (qt - 48) * 4;
  const int pu = bh * 144 + off;
  const int d = threadIdx.x;
  const int b = bh >> 4, h = bh & 15;
  for (int q = 0; q < 32; ++q) {
    float mx = -INFINITY;
    for (int u = 0; u < nu; ++u) mx = fmaxf(mx, ml[(pu + u) * 32 + q].x);
    float den = 0.f, accum = 0.f;
    for (int u = 0; u < nu; ++u) {
      const float2 t = ml[(pu + u) * 32 + q];
      const float wgt = __builtin_amdgcn_exp2f(t.x - mx);
      den += wgt * t.y;
      accum += wgt * (float)Opart[((size_t)(pu + u) * 32 + q) * 64 + d];
    }
    O[((size_t)(b * 2048 + qt * 32 + q)) * 1024 + h * 64 + d] = (f16)(accum / den);
  }
}

extern "C" void kernel_launch(void* const* d_in, const int* in_sizes, int n_in,
                              void* d_out, int out_size, void* d_ws, size_t ws_size,
                              hipStream_t stream) {
  const float* x = (const float*)d_in[0];     // [2][2048][1024]
  const float* Wqkv = (const float*)d_in[1];  // [1024][3072]
  const float* Wout = (const float*)d_in[2];  // [1024][1024]

  char* p = (char*)d_ws;
  f16* Xb = (f16*)p;      p += (size_t)4096 * 1024 * 2;      // x in f16
  f16* Wqkvt = (f16*)p;   p += (size_t)3072 * 1024 * 2;      // W_qkv^T f16, rows e'=[k][h][d]
  f16* Woutt = (f16*)p;   p += (size_t)1024 * 1024 * 2;      // W_out^T f16
  f16* Qp = (f16*)p;      p += (size_t)32 * 2048 * 64 * 2;   // [b*h][n][d], scaled 1/8*log2e
  f16* Kp = (f16*)p;      p += (size_t)32 * 2048 * 64 * 2;   // [b*h][n][d]
  f16* Vt = (f16*)p;      p += (size_t)32 * 64 * 2048 * 2;   // [b*h][d][n]
  f16* O = (f16*)p;       p += (size_t)4096 * 1024 * 2;      // [b*n][h*64+d]
  f16* Opart = (f16*)p;   p += (size_t)4608 * 2048 * 2;      // partial O [unit][32][64]
  float2* ml = (float2*)p; p += (size_t)4608 * 32 * 8;       // per-row (m,l)

  k_cvt<<<4096, 256, 0, stream>>>((const float4*)x, (f16x4*)Xb, 4096 * 1024 / 4);
  k_transpose_qkv<<<dim3(96, 32), dim3(32, 8), 0, stream>>>(Wqkv, Wqkvt);
  k_transpose<<<dim3(32, 32), dim3(32, 8), 0, stream>>>(Wout, Woutt, 1024, 1024);
  k_gemm<0><<<dim3(24, 32), 256, 0, stream>>>(Xb, Wqkvt, nullptr, Qp, Kp, Vt);
  k_attn<<<5120, 64, 0, stream>>>(Qp, Kp, Vt, O, Opart, ml);
  k_merge<<<1536, 64, 0, stream>>>(Opart, ml, O);
  k_gemm<1><<<dim3(8, 32), 256, 0, stream>>>(O, Woutt, (float*)d_out, nullptr, nullptr, nullptr);
}